// Round 8
// baseline (212.955 us; speedup 1.0000x reference)
//
#include <hip/hip_runtime.h>
#include <hip/hip_bf16.h>

#define S_LEN 4096
#define DM    768
#define NH    12
#define DKH   64

typedef __attribute__((ext_vector_type(8))) short short8;
typedef __attribute__((ext_vector_type(4))) float f32x4;

__device__ __forceinline__ short f2bf(float f) {
    union { float f; unsigned u; } v; v.f = f;
    unsigned r = (v.u + 0x7FFFu + ((v.u >> 16) & 1u)) >> 16;
    return (short)r;
}

#define MFMA16(a, b, c) __builtin_amdgcn_mfma_f32_16x16x32_bf16((a), (b), (c), 0, 0, 0)

// ------------------------------------------------- fused prep (1 dispatch)
// blocks [0,3072): X ; [3072,3648): Wq ; [3648,4224): Wk ; [4224,4800): Wv ;
// [4800,5376): Wo ; [5376,5888): rope table.
__device__ __forceinline__ void cvt4(const float* __restrict__ s,
                                     short* __restrict__ d, int i) {
    float4 v = *reinterpret_cast<const float4*>(s + i);
    short4 o;
    o.x = f2bf(v.x); o.y = f2bf(v.y); o.z = f2bf(v.z); o.w = f2bf(v.w);
    *reinterpret_cast<short4*>(d + i) = o;
}

__global__ __launch_bounds__(256) void prep_k(
    const float* __restrict__ X, const float* __restrict__ Wq,
    const float* __restrict__ Wk, const float* __restrict__ Wv,
    const float* __restrict__ Wo, const int* __restrict__ pos,
    short* __restrict__ Xbf, short* __restrict__ Wqb, short* __restrict__ Wkb,
    short* __restrict__ Wvb, short* __restrict__ Wob, float2* __restrict__ rt) {
    const int bx = blockIdx.x, tid = threadIdx.x;
    if (bx < 3072)      cvt4(X,  Xbf, bx * 1024 + tid * 4);
    else if (bx < 3648) cvt4(Wq, Wqb, (bx - 3072) * 1024 + tid * 4);
    else if (bx < 4224) cvt4(Wk, Wkb, (bx - 3648) * 1024 + tid * 4);
    else if (bx < 4800) cvt4(Wv, Wvb, (bx - 4224) * 1024 + tid * 4);
    else if (bx < 5376) cvt4(Wo, Wob, (bx - 4800) * 1024 + tid * 4);
    else {
        int idx = (bx - 5376) * 256 + tid;
        int s = idx >> 5, i = idx & 31;
        int p = pos[s]; p = p < 0 ? 0 : (p > 4095 ? 4095 : p);
        double inv = pow(10000.0, -(double)i / 32.0);
        float ang = (float)((double)p * inv);
        rt[idx] = make_float2(cosf(ang), sinf(ang));
    }
}

// ---------------------------------------------------------------- GEMM core
// 128x128 tile, BK=64 (12 K-steps, half the barriers of BK=32),
// global_load_lds(16B) with XOR-chunk swizzle on the GLOBAL source.
__device__ __forceinline__ void gemm_mainloop(const short* __restrict__ A,
                                              const short* __restrict__ B,
                                              short* Al, short* Bl,
                                              int m0, int n0, int t,
                                              f32x4 acc[4][4]) {
    const int wave = t >> 6, lane = t & 63;
    const int wm = (wave >> 1) * 64, wn = (wave & 1) * 64;
    const int l15 = lane & 15, lg = lane >> 4;
    const int grow = lane >> 3;               // row-in-8
    const int gch = (lane & 7) ^ grow;        // swizzled 16B chunk (row&7==grow)
    const int dsto = wave * 512 + lane * 8;   // shorts; + i*2048 per round
    for (int k0 = 0; k0 < DM; k0 += 64) {
        __syncthreads();
#pragma unroll
        for (int i = 0; i < 4; ++i) {
            int row = i * 32 + wave * 8 + grow;
            __builtin_amdgcn_global_load_lds(
                (const __attribute__((address_space(1))) void*)&A[(m0 + row) * DM + k0 + gch * 8],
                (__attribute__((address_space(3))) void*)(Al + i * 2048 + dsto), 16, 0, 0);
            __builtin_amdgcn_global_load_lds(
                (const __attribute__((address_space(1))) void*)&B[(n0 + row) * DM + k0 + gch * 8],
                (__attribute__((address_space(3))) void*)(Bl + i * 2048 + dsto), 16, 0, 0);
        }
        __syncthreads();
#pragma unroll
        for (int kh = 0; kh < 2; ++kh) {
            const int c8 = (kh * 4 + lg) ^ (l15 & 7);
            short8 af[4], bf[4];
#pragma unroll
            for (int m = 0; m < 4; ++m)
                af[m] = *reinterpret_cast<const short8*>(Al + (wm + m * 16 + l15) * 64 + c8 * 8);
#pragma unroll
            for (int n = 0; n < 4; ++n)
                bf[n] = *reinterpret_cast<const short8*>(Bl + (wn + n * 16 + l15) * 64 + c8 * 8);
#pragma unroll
            for (int m = 0; m < 4; ++m)
#pragma unroll
                for (int n = 0; n < 4; ++n)
                    acc[m][n] = MFMA16(af[m], bf[n], acc[m][n]);
        }
    }
}

// QKV projection + fused RoPE (+ 1/8*log2e on Q) + fused V-transpose.
// grid = (6, 32, 3)
__global__ __launch_bounds__(256) void gemm_qkv_k(
    const short* __restrict__ Xbf, const short* __restrict__ Wq,
    const short* __restrict__ Wk, const short* __restrict__ Wv,
    const float2* __restrict__ rt,
    short* __restrict__ Q, short* __restrict__ K, short* __restrict__ Vt) {
    __shared__ __align__(16) short Al[128 * 64];
    __shared__ __align__(16) short Bl[128 * 64];
    const int mat = blockIdx.z;
    const short* B = mat == 0 ? Wq : (mat == 1 ? Wk : Wv);
    const int m0 = blockIdx.y * 128, n0 = blockIdx.x * 128;
    const int t = threadIdx.x;
    f32x4 acc[4][4] = {};
    gemm_mainloop(Xbf, B, Al, Bl, m0, n0, t, acc);
    const int wave = t >> 6, lane = t & 63;
    const int wm = (wave >> 1) * 64, wn = (wave & 1) * 64;
    const int l15 = lane & 15, lg = lane >> 4;
    if (mat < 2) {
        short* Out = mat == 0 ? Q : K;
        const float qs = 0.125f * 1.44269504088896f;  // 1/sqrt(dk) * log2(e)
#pragma unroll
        for (int m = 0; m < 4; ++m) {
#pragma unroll
            for (int n = 0; n < 4; ++n) {
                int col = n0 + wn + n * 16 + l15;
                int h = col >> 6, d = col & 63;
#pragma unroll
                for (int j = 0; j < 4; ++j) {
                    int srow = m0 + wm + m * 16 + lg * 4 + j;
                    float v = acc[m][n][j];
                    float other = __shfl_xor(v, 1);
                    float2 cs = rt[srow * 32 + (d >> 1)];
                    v = (d & 1) ? (other * cs.y + v * cs.x)
                                : (v * cs.x - other * cs.y);
                    if (mat == 0) v *= qs;
                    Out[(h * S_LEN + srow) * DKH + d] = f2bf(v);
                }
            }
        }
    } else {
#pragma unroll
        for (int m = 0; m < 4; ++m)
#pragma unroll
            for (int n = 0; n < 4; ++n) {
                int col = n0 + wn + n * 16 + l15;
                int h = col >> 6, d = col & 63;
                int srow0 = m0 + wm + m * 16 + lg * 4;
                short4 b;
                b.x = f2bf(acc[m][n][0]); b.y = f2bf(acc[m][n][1]);
                b.z = f2bf(acc[m][n][2]); b.w = f2bf(acc[m][n][3]);
                *reinterpret_cast<short4*>(&Vt[(size_t)(h * DKH + d) * S_LEN + srow0]) = b;
            }
    }
}

// Output projection. grid = (6, 32)
__global__ __launch_bounds__(256) void gemm_out_k(const short* __restrict__ Ab,
                                                  const short* __restrict__ Wo,
                                                  float* __restrict__ out) {
    __shared__ __align__(16) short Al[128 * 64];
    __shared__ __align__(16) short Bl[128 * 64];
    const int m0 = blockIdx.y * 128, n0 = blockIdx.x * 128;
    const int t = threadIdx.x;
    f32x4 acc[4][4] = {};
    gemm_mainloop(Ab, Wo, Al, Bl, m0, n0, t, acc);
    const int wave = t >> 6, lane = t & 63;
    const int wm = (wave >> 1) * 64, wn = (wave & 1) * 64;
    const int l15 = lane & 15, lg = lane >> 4;
#pragma unroll
    for (int m = 0; m < 4; ++m)
#pragma unroll
        for (int n = 0; n < 4; ++n)
#pragma unroll
            for (int j = 0; j < 4; ++j) {
                int srow = m0 + wm + m * 16 + lg * 4 + j;
                int col = n0 + wn + n * 16 + l15;
                out[srow * DM + col] = acc[m][n][j];
            }
}

// ---------------------------------------------------------------- attention
__device__ __forceinline__ void stage64(const short* __restrict__ gRow0,
                                        int rowStride, short* lbuf,
                                        int wave, int lane) {
#pragma unroll
    for (int i = 0; i < 2; ++i) {
        int c = wave + i * 4;                     // 1KB chunk 0..7
        int row = c * 8 + (lane >> 3);            // tile row 0..63
        int gch = (lane & 7) ^ (lane >> 3);       // swizzled 16B chunk in row
        const short* src = gRow0 + (long)row * rowStride + gch * 8;
        short* dst = lbuf + c * 512 + lane * 8;   // linear: row*64 + chunk*8
        __builtin_amdgcn_global_load_lds(
            (const __attribute__((address_space(1))) void*)src,
            (__attribute__((address_space(3))) void*)dst, 16, 0, 0);
    }
}

// Swapped-operand causal flash attention, 2 Q-frags per wave (32 q-rows),
// counted-covered pipeline (stage t+1 before compute, vmcnt(0)+raw barrier
// after). grid = 32*12 heavy-first, 4 waves, 128 q-rows/block, KV tile 64.
__global__ __launch_bounds__(256, 3) void attn_k(const short* __restrict__ Q,
                                                 const short* __restrict__ K,
                                                 const short* __restrict__ Vt,
                                                 short* __restrict__ Aout) {
    const int bx = blockIdx.x;
    const int h = bx % NH;
    const int qb = (S_LEN / 128 - 1) - (bx / NH);   // heaviest blocks first
    const int t = threadIdx.x;
    const int wave = t >> 6, lane = t & 63;
    const int l15 = lane & 15, lg = lane >> 4;
    const int q0w = qb * 128 + wave * 32;

    // KV dbuf 32768B + P 4*32*72*2=18432B = 51200B; epilogue reuses base.
    __shared__ __align__(16) char SMEM[2 * 2 * 64 * 64 * 2 + 4 * 32 * 72 * 2];
    short* KVl = (short*)SMEM;                 // [buf][K|V][64*64]
    short* Pl = (short*)(SMEM + 32768);        // [wave][32][72]

    const short* Kh = K + (size_t)h * S_LEN * DKH;
    const short* Vh = Vt + (size_t)h * DKH * S_LEN;

    short8 qf[2][2];
#pragma unroll
    for (int f = 0; f < 2; ++f)
#pragma unroll
        for (int ks = 0; ks < 2; ++ks)
            qf[f][ks] = *reinterpret_cast<const short8*>(
                &Q[(h * S_LEN + q0w + f * 16 + l15) * DKH + ks * 32 + lg * 8]);

    f32x4 o[2][4] = {};
    float mrun[2] = {-1e30f, -1e30f}, lpart[2] = {0.f, 0.f};
    const int nt = 2 * qb + 2;

    stage64(Kh, DKH, KVl, wave, lane);
    stage64(Vh, S_LEN, KVl + 4096, wave, lane);
    __syncthreads();

    for (int tile = 0; tile < nt; ++tile) {
        const int cur = tile & 1;
        if (tile + 1 < nt) {
            stage64(Kh + (size_t)(tile + 1) * 64 * DKH, DKH,
                    KVl + (cur ^ 1) * 8192, wave, lane);
            stage64(Vh + (tile + 1) * 64, S_LEN,
                    KVl + (cur ^ 1) * 8192 + 4096, wave, lane);
        }
        __builtin_amdgcn_sched_barrier(0);
        const char* Kb = (const char*)(KVl + cur * 8192);
        const char* Vb = (const char*)(KVl + cur * 8192 + 4096);

        // ---- S^T = K Q^T, both q-frags share each K fragment
        f32x4 s[2][4] = {};
        __builtin_amdgcn_s_setprio(1);
#pragma unroll
        for (int ks = 0; ks < 2; ++ks)
#pragma unroll
            for (int n = 0; n < 4; ++n) {
                int r = n * 16 + l15;
                int c8 = (ks * 4 + lg) ^ (r & 7);
                short8 kf = *reinterpret_cast<const short8*>(Kb + r * 128 + c8 * 16);
                s[0][n] = MFMA16(kf, qf[0][ks], s[0][n]);
                s[1][n] = MFMA16(kf, qf[1][ks], s[1][n]);
            }
        __builtin_amdgcn_s_setprio(0);

        // ---- causal mask (last two tiles only)
        if (tile >= nt - 2) {
#pragma unroll
            for (int f = 0; f < 2; ++f) {
                const int q = q0w + f * 16 + l15;
#pragma unroll
                for (int n = 0; n < 4; ++n)
#pragma unroll
                    for (int j = 0; j < 4; ++j)
                        if (tile * 64 + n * 16 + lg * 4 + j > q) s[f][n][j] = -1e30f;
            }
        }

        // ---- per-lane local max per frag; defer path: no cross-lane ops
        float mt[2];
#pragma unroll
        for (int f = 0; f < 2; ++f) {
            mt[f] = fmaxf(fmaxf(fmaxf(s[f][0][0], s[f][0][1]), fmaxf(s[f][0][2], s[f][0][3])),
                          fmaxf(fmaxf(s[f][1][0], s[f][1][1]), fmaxf(s[f][1][2], s[f][1][3])));
            mt[f] = fmaxf(mt[f],
                          fmaxf(fmaxf(fmaxf(s[f][2][0], s[f][2][1]), fmaxf(s[f][2][2], s[f][2][3])),
                                fmaxf(fmaxf(s[f][3][0], s[f][3][1]), fmaxf(s[f][3][2], s[f][3][3]))));
        }

        if (__all((mt[0] <= mrun[0] + 8.f) && (mt[1] <= mrun[1] + 8.f))) {
#pragma unroll
            for (int f = 0; f < 2; ++f)
#pragma unroll
                for (int n = 0; n < 4; ++n)
#pragma unroll
                    for (int j = 0; j < 4; ++j) {
                        float p = exp2f(s[f][n][j] - mrun[f]);
                        s[f][n][j] = p;
                        lpart[f] += p;
                    }
        } else {
#pragma unroll
            for (int f = 0; f < 2; ++f) {
                float mm = fmaxf(mt[f], __shfl_xor(mt[f], 16));
                mm = fmaxf(mm, __shfl_xor(mm, 32));
                float mnew = fmaxf(mrun[f], mm);
                float alpha = exp2f(mrun[f] - mnew);
                lpart[f] *= alpha;
#pragma unroll
                for (int n = 0; n < 4; ++n)
#pragma unroll
                    for (int j = 0; j < 4; ++j) {
                        float p = exp2f(s[f][n][j] - mnew);
                        s[f][n][j] = p;
                        lpart[f] += p;
                    }
#pragma unroll
                for (int n = 0; n < 4; ++n)
#pragma unroll
                    for (int j = 0; j < 4; ++j) o[f][n][j] *= alpha;
                mrun[f] = mnew;
            }
        }

        // ---- P^T -> per-wave LDS (same-wave RAW; no barrier)
#pragma unroll
        for (int f = 0; f < 2; ++f)
#pragma unroll
            for (int n = 0; n < 4; ++n) {
                unsigned p0, p1;
                asm("v_cvt_pk_bf16_f32 %0, %1, %2" : "=v"(p0) : "v"(s[f][n][0]), "v"(s[f][n][1]));
                asm("v_cvt_pk_bf16_f32 %0, %1, %2" : "=v"(p1) : "v"(s[f][n][2]), "v"(s[f][n][3]));
                uint2 w; w.x = p0; w.y = p1;
                *reinterpret_cast<uint2*>(
                    &Pl[(wave * 32 + f * 16 + l15) * 72 + n * 16 + lg * 4]) = w;
            }

        // ---- O^T += V^T P^T, both P-frags share each V fragment
        __builtin_amdgcn_s_setprio(1);
#pragma unroll
        for (int ks = 0; ks < 2; ++ks) {
            short8 pa0 = *reinterpret_cast<const short8*>(
                &Pl[(wave * 32 + l15) * 72 + ks * 32 + lg * 8]);
            short8 pa1 = *reinterpret_cast<const short8*>(
                &Pl[(wave * 32 + 16 + l15) * 72 + ks * 32 + lg * 8]);
#pragma unroll
            for (int n = 0; n < 4; ++n) {
                int r = n * 16 + l15;
                int c8 = (ks * 4 + lg) ^ (r & 7);
                short8 vf = *reinterpret_cast<const short8*>(Vb + r * 128 + c8 * 16);
                o[0][n] = MFMA16(vf, pa0, o[0][n]);
                o[1][n] = MFMA16(vf, pa1, o[1][n]);
            }
        }
        __builtin_amdgcn_s_setprio(0);

        // ---- covered fence + raw barrier (no early drain)
        asm volatile("s_waitcnt vmcnt(0)" ::: "memory");
        __builtin_amdgcn_sched_barrier(0);
        __builtin_amdgcn_s_barrier();
    }

    // ---- combine deferred per-lane sums (once)
    float inv[2];
#pragma unroll
    for (int f = 0; f < 2; ++f) {
        float ls = lpart[f] + __shfl_xor(lpart[f], 16);
        ls += __shfl_xor(ls, 32);
        inv[f] = 1.f / ls;
    }

    __syncthreads();
    float* Ol = (float*)SMEM + wave * (32 * 68);
#pragma unroll
    for (int f = 0; f < 2; ++f)
#pragma unroll
        for (int n = 0; n < 4; ++n) {
            float4 w;
            w.x = o[f][n][0] * inv[f]; w.y = o[f][n][1] * inv[f];
            w.z = o[f][n][2] * inv[f]; w.w = o[f][n][3] * inv[f];
            *reinterpret_cast<float4*>(&Ol[(f * 16 + l15) * 68 + n * 16 + lg * 4]) = w;
        }
#pragma unroll
    for (int kk = 0; kk < 8; ++kk) {
        int r = (lane >> 2) + (kk & 1) * 16;
        int c0 = (lane & 3) * 4 + (kk >> 1) * 16;
        float4 v = *reinterpret_cast<const float4*>(&Ol[r * 68 + c0]);
        short4 b;
        b.x = f2bf(v.x); b.y = f2bf(v.y); b.z = f2bf(v.z); b.w = f2bf(v.w);
        *reinterpret_cast<short4*>(
            &Aout[(size_t)(q0w + r) * DM + h * DKH + c0]) = b;
    }
}

// ---------------------------------------------------------------- launcher
extern "C" void kernel_launch(void* const* d_in, const int* in_sizes, int n_in,
                              void* d_out, int out_size, void* d_ws, size_t ws_size,
                              hipStream_t stream) {
    const float* X  = (const float*)d_in[0];
    const int*   pos = (const int*)d_in[1];
    const float* Wq = (const float*)d_in[2];
    const float* Wk = (const float*)d_in[3];
    const float* Wv = (const float*)d_in[4];
    const float* Wo = (const float*)d_in[5];
    float* out = (float*)d_out;

    char* ws = (char*)d_ws;
    short* Xbf = (short*)ws;  ws += (size_t)S_LEN * DM * 2;
    short* Wqb = (short*)ws;  ws += (size_t)DM * DM * 2;
    short* Wkb = (short*)ws;  ws += (size_t)DM * DM * 2;
    short* Wvb = (short*)ws;  ws += (size_t)DM * DM * 2;
    short* Wob = (short*)ws;  ws += (size_t)DM * DM * 2;
    float2* rt = (float2*)ws; ws += (size_t)S_LEN * 32 * 8;
    short* Qb  = (short*)ws;  ws += (size_t)NH * S_LEN * DKH * 2;
    short* Kb  = (short*)ws;  ws += (size_t)NH * S_LEN * DKH * 2;
    short* Vtb = (short*)ws;  ws += (size_t)NH * S_LEN * DKH * 2;
    short* Ab  = (short*)ws;  ws += (size_t)S_LEN * DM * 2;

    prep_k<<<5888, 256, 0, stream>>>(X, Wq, Wk, Wv, Wo, pos,
                                     Xbf, Wqb, Wkb, Wvb, Wob, rt);
    gemm_qkv_k<<<dim3(6, 32, 3), 256, 0, stream>>>(Xbf, Wqb, Wkb, Wvb, rt, Qb, Kb, Vtb);
    attn_k<<<dim3(32 * NH), 256, 0, stream>>>(Qb, Kb, Vtb, Ab);
    gemm_out_k<<<dim3(6, 32), 256, 0, stream>>>(Ab, Wob, out);
}

// Round 9
// 147.300 us; speedup vs baseline: 1.4457x; 1.4457x over previous
//
#include <hip/hip_runtime.h>
#include <hip/hip_bf16.h>

#define S_LEN 4096
#define DM    768
#define NH    12
#define DKH   64

typedef __attribute__((ext_vector_type(8))) short short8;
typedef __attribute__((ext_vector_type(4))) float f32x4;

__device__ __forceinline__ short f2bf(float f) {
    union { float f; unsigned u; } v; v.f = f;
    unsigned r = (v.u + 0x7FFFu + ((v.u >> 16) & 1u)) >> 16;
    return (short)r;
}

#define MFMA16(a, b, c) __builtin_amdgcn_mfma_f32_16x16x32_bf16((a), (b), (c), 0, 0, 0)

// ------------------------------------------------- fused prep (1 dispatch)
__device__ __forceinline__ void cvt4(const float* __restrict__ s,
                                     short* __restrict__ d, int i) {
    float4 v = *reinterpret_cast<const float4*>(s + i);
    short4 o;
    o.x = f2bf(v.x); o.y = f2bf(v.y); o.z = f2bf(v.z); o.w = f2bf(v.w);
    *reinterpret_cast<short4*>(d + i) = o;
}

__global__ __launch_bounds__(256) void prep_k(
    const float* __restrict__ X, const float* __restrict__ Wq,
    const float* __restrict__ Wk, const float* __restrict__ Wv,
    const float* __restrict__ Wo, const int* __restrict__ pos,
    short* __restrict__ Xbf, short* __restrict__ Wqb, short* __restrict__ Wkb,
    short* __restrict__ Wvb, short* __restrict__ Wob, float2* __restrict__ rt) {
    const int bx = blockIdx.x, tid = threadIdx.x;
    if (bx < 3072)      cvt4(X,  Xbf, bx * 1024 + tid * 4);
    else if (bx < 3648) cvt4(Wq, Wqb, (bx - 3072) * 1024 + tid * 4);
    else if (bx < 4224) cvt4(Wk, Wkb, (bx - 3648) * 1024 + tid * 4);
    else if (bx < 4800) cvt4(Wv, Wvb, (bx - 4224) * 1024 + tid * 4);
    else if (bx < 5376) cvt4(Wo, Wob, (bx - 4800) * 1024 + tid * 4);
    else {
        int idx = (bx - 5376) * 256 + tid;
        int s = idx >> 5, i = idx & 31;
        int p = pos[s]; p = p < 0 ? 0 : (p > 4095 ? 4095 : p);
        double inv = pow(10000.0, -(double)i / 32.0);
        float ang = (float)((double)p * inv);
        rt[idx] = make_float2(cosf(ang), sinf(ang));
    }
}

// ---------------------------------------------------------------- GEMM core
// 128x128 tile, BK=64 (12 K-steps), global_load_lds(16B) with XOR-chunk
// swizzle on the GLOBAL source (linear LDS dest, rule #21).
__device__ __forceinline__ void gemm_mainloop(const short* __restrict__ A,
                                              const short* __restrict__ B,
                                              short* Al, short* Bl,
                                              int m0, int n0, int t,
                                              f32x4 acc[4][4]) {
    const int wave = t >> 6, lane = t & 63;
    const int wm = (wave >> 1) * 64, wn = (wave & 1) * 64;
    const int l15 = lane & 15, lg = lane >> 4;
    const int grow = lane >> 3;               // row-in-8
    const int gch = (lane & 7) ^ grow;        // swizzled 16B chunk
    const int dsto = wave * 512 + lane * 8;
    for (int k0 = 0; k0 < DM; k0 += 64) {
        __syncthreads();
#pragma unroll
        for (int i = 0; i < 4; ++i) {
            int row = i * 32 + wave * 8 + grow;
            __builtin_amdgcn_global_load_lds(
                (const __attribute__((address_space(1))) void*)&A[(m0 + row) * DM + k0 + gch * 8],
                (__attribute__((address_space(3))) void*)(Al + i * 2048 + dsto), 16, 0, 0);
            __builtin_amdgcn_global_load_lds(
                (const __attribute__((address_space(1))) void*)&B[(n0 + row) * DM + k0 + gch * 8],
                (__attribute__((address_space(3))) void*)(Bl + i * 2048 + dsto), 16, 0, 0);
        }
        __syncthreads();
#pragma unroll
        for (int kh = 0; kh < 2; ++kh) {
            const int c8 = (kh * 4 + lg) ^ (l15 & 7);
            short8 af[4], bf[4];
#pragma unroll
            for (int m = 0; m < 4; ++m)
                af[m] = *reinterpret_cast<const short8*>(Al + (wm + m * 16 + l15) * 64 + c8 * 8);
#pragma unroll
            for (int n = 0; n < 4; ++n)
                bf[n] = *reinterpret_cast<const short8*>(Bl + (wn + n * 16 + l15) * 64 + c8 * 8);
#pragma unroll
            for (int m = 0; m < 4; ++m)
#pragma unroll
                for (int n = 0; n < 4; ++n)
                    acc[m][n] = MFMA16(af[m], bf[n], acc[m][n]);
        }
    }
}

// QKV projection + fused RoPE (+ 1/8*log2e on Q) + fused V-transpose.
// grid = (6, 32, 3)
__global__ __launch_bounds__(256) void gemm_qkv_k(
    const short* __restrict__ Xbf, const short* __restrict__ Wq,
    const short* __restrict__ Wk, const short* __restrict__ Wv,
    const float2* __restrict__ rt,
    short* __restrict__ Q, short* __restrict__ K, short* __restrict__ Vt) {
    __shared__ __align__(16) short Al[128 * 64];
    __shared__ __align__(16) short Bl[128 * 64];
    const int mat = blockIdx.z;
    const short* B = mat == 0 ? Wq : (mat == 1 ? Wk : Wv);
    const int m0 = blockIdx.y * 128, n0 = blockIdx.x * 128;
    const int t = threadIdx.x;
    f32x4 acc[4][4] = {};
    gemm_mainloop(Xbf, B, Al, Bl, m0, n0, t, acc);
    const int wave = t >> 6, lane = t & 63;
    const int wm = (wave >> 1) * 64, wn = (wave & 1) * 64;
    const int l15 = lane & 15, lg = lane >> 4;
    if (mat < 2) {
        short* Out = mat == 0 ? Q : K;
        const float qs = 0.125f * 1.44269504088896f;  // 1/sqrt(dk) * log2(e)
#pragma unroll
        for (int m = 0; m < 4; ++m) {
#pragma unroll
            for (int n = 0; n < 4; ++n) {
                int col = n0 + wn + n * 16 + l15;
                int h = col >> 6, d = col & 63;
#pragma unroll
                for (int j = 0; j < 4; ++j) {
                    int srow = m0 + wm + m * 16 + lg * 4 + j;
                    float v = acc[m][n][j];
                    float other = __shfl_xor(v, 1);
                    float2 cs = rt[srow * 32 + (d >> 1)];
                    v = (d & 1) ? (other * cs.y + v * cs.x)
                                : (v * cs.x - other * cs.y);
                    if (mat == 0) v *= qs;
                    Out[(h * S_LEN + srow) * DKH + d] = f2bf(v);
                }
            }
        }
    } else {
#pragma unroll
        for (int m = 0; m < 4; ++m)
#pragma unroll
            for (int n = 0; n < 4; ++n) {
                int col = n0 + wn + n * 16 + l15;
                int h = col >> 6, d = col & 63;
                int srow0 = m0 + wm + m * 16 + lg * 4;
                short4 b;
                b.x = f2bf(acc[m][n][0]); b.y = f2bf(acc[m][n][1]);
                b.z = f2bf(acc[m][n][2]); b.w = f2bf(acc[m][n][3]);
                *reinterpret_cast<short4*>(&Vt[(size_t)(h * DKH + d) * S_LEN + srow0]) = b;
            }
    }
}

// Output projection. grid = (6, 32)
__global__ __launch_bounds__(256) void gemm_out_k(const short* __restrict__ Ab,
                                                  const short* __restrict__ Wo,
                                                  float* __restrict__ out) {
    __shared__ __align__(16) short Al[128 * 64];
    __shared__ __align__(16) short Bl[128 * 64];
    const int m0 = blockIdx.y * 128, n0 = blockIdx.x * 128;
    const int t = threadIdx.x;
    f32x4 acc[4][4] = {};
    gemm_mainloop(Ab, Wo, Al, Bl, m0, n0, t, acc);
    const int wave = t >> 6, lane = t & 63;
    const int wm = (wave >> 1) * 64, wn = (wave & 1) * 64;
    const int l15 = lane & 15, lg = lane >> 4;
#pragma unroll
    for (int m = 0; m < 4; ++m)
#pragma unroll
        for (int n = 0; n < 4; ++n)
#pragma unroll
            for (int j = 0; j < 4; ++j) {
                int srow = m0 + wm + m * 16 + lg * 4 + j;
                int col = n0 + wn + n * 16 + l15;
                out[srow * DM + col] = acc[m][n][j];
            }
}

// ---------------------------------------------------------------- attention
__device__ __forceinline__ void stage64(const short* __restrict__ gRow0,
                                        int rowStride, short* lbuf,
                                        int wave, int lane) {
#pragma unroll
    for (int i = 0; i < 2; ++i) {
        int c = wave + i * 4;                     // 1KB chunk 0..7
        int row = c * 8 + (lane >> 3);            // tile row 0..63
        int gch = (lane & 7) ^ (lane >> 3);       // swizzled 16B chunk in row
        const short* src = gRow0 + (long)row * rowStride + gch * 8;
        short* dst = lbuf + c * 512 + lane * 8;   // linear: row*64 + chunk*8
        __builtin_amdgcn_global_load_lds(
            (const __attribute__((address_space(1))) void*)src,
            (__attribute__((address_space(3))) void*)dst, 16, 0, 0);
    }
}

// R7 attn (known-good 88.7us): swapped-operand causal flash attention,
// counted-covered pipeline (stage t+1 before compute; vmcnt(0) after
// compute + ONE raw s_barrier). grid = 64*12 heavy-first, 4 waves,
// 16 q-rows/wave, KV tile 64, K/V double-buffered (42.5KB, 3 blocks/CU).
__global__ __launch_bounds__(256) void attn_k(const short* __restrict__ Q,
                                              const short* __restrict__ K,
                                              const short* __restrict__ Vt,
                                              short* __restrict__ Aout) {
    const int bx = blockIdx.x;
    const int h = bx % NH;
    const int qb = (S_LEN / 64 - 1) - (bx / NH);    // heaviest blocks first
    const int t = threadIdx.x;
    const int wave = t >> 6, lane = t & 63;
    const int l15 = lane & 15, lg = lane >> 4;
    const int q0w = qb * 64 + wave * 16;

    __shared__ __align__(16) short KVl[2][2][64 * 64];  // [buf][K|V]
    __shared__ __align__(16) short Pl[4][16][76];

    const short* Kh = K + (size_t)h * S_LEN * DKH;
    const short* Vh = Vt + (size_t)h * DKH * S_LEN;

    short8 qf[2];
#pragma unroll
    for (int ks = 0; ks < 2; ++ks)
        qf[ks] = *reinterpret_cast<const short8*>(
            &Q[(h * S_LEN + q0w + l15) * DKH + ks * 32 + lg * 8]);

    f32x4 o[4] = {};
    float mrun = -1e30f, lpart = 0.f;
    const int nt = qb + 1;

    stage64(Kh, DKH, KVl[0][0], wave, lane);
    stage64(Vh, S_LEN, KVl[0][1], wave, lane);
    __syncthreads();

    for (int tile = 0; tile < nt; ++tile) {
        const int cur = tile & 1;
        if (tile + 1 < nt) {
            stage64(Kh + (size_t)(tile + 1) * 64 * DKH, DKH, KVl[cur ^ 1][0], wave, lane);
            stage64(Vh + (tile + 1) * 64, S_LEN, KVl[cur ^ 1][1], wave, lane);
        }
        __builtin_amdgcn_sched_barrier(0);   // pin issue point
        const char* Kb = (const char*)KVl[cur][0];
        const char* Vb = (const char*)KVl[cur][1];

        // ---- S^T = K Q^T (Q pre-scaled by 1/8*log2e)
        f32x4 s[4] = {};
        __builtin_amdgcn_s_setprio(1);
#pragma unroll
        for (int ks = 0; ks < 2; ++ks)
#pragma unroll
            for (int n = 0; n < 4; ++n) {
                int r = n * 16 + l15;
                int c8 = (ks * 4 + lg) ^ (r & 7);
                short8 kf = *reinterpret_cast<const short8*>(Kb + r * 128 + c8 * 16);
                s[n] = MFMA16(kf, qf[ks], s[n]);
            }
        __builtin_amdgcn_s_setprio(0);

        // ---- causal mask (diagonal tile only)
        if (tile == qb) {
            const int q = q0w + l15;
#pragma unroll
            for (int n = 0; n < 4; ++n)
#pragma unroll
                for (int j = 0; j < 4; ++j)
                    if (tile * 64 + n * 16 + lg * 4 + j > q) s[n][j] = -1e30f;
        }

        // ---- per-lane local max; defer path has NO cross-lane ops
        float mt = fmaxf(fmaxf(fmaxf(s[0][0], s[0][1]), fmaxf(s[0][2], s[0][3])),
                         fmaxf(fmaxf(s[1][0], s[1][1]), fmaxf(s[1][2], s[1][3])));
        mt = fmaxf(mt, fmaxf(fmaxf(fmaxf(s[2][0], s[2][1]), fmaxf(s[2][2], s[2][3])),
                             fmaxf(fmaxf(s[3][0], s[3][1]), fmaxf(s[3][2], s[3][3]))));

        if (__all(mt <= mrun + 8.f)) {
#pragma unroll
            for (int n = 0; n < 4; ++n)
#pragma unroll
                for (int j = 0; j < 4; ++j) {
                    float p = exp2f(s[n][j] - mrun);
                    s[n][j] = p;
                    lpart += p;
                }
        } else {
            float mm = fmaxf(mt, __shfl_xor(mt, 16));
            mm = fmaxf(mm, __shfl_xor(mm, 32));
            float mnew = fmaxf(mrun, mm);
            float alpha = exp2f(mrun - mnew);
            lpart *= alpha;
#pragma unroll
            for (int n = 0; n < 4; ++n)
#pragma unroll
                for (int j = 0; j < 4; ++j) {
                    float p = exp2f(s[n][j] - mnew);
                    s[n][j] = p;
                    lpart += p;
                }
#pragma unroll
            for (int n = 0; n < 4; ++n)
#pragma unroll
                for (int j = 0; j < 4; ++j) o[n][j] *= alpha;
            mrun = mnew;
        }

        // ---- P^T -> per-wave LDS (same-wave RAW; no barrier needed)
#pragma unroll
        for (int n = 0; n < 4; ++n) {
            unsigned p0, p1;
            asm("v_cvt_pk_bf16_f32 %0, %1, %2" : "=v"(p0) : "v"(s[n][0]), "v"(s[n][1]));
            asm("v_cvt_pk_bf16_f32 %0, %1, %2" : "=v"(p1) : "v"(s[n][2]), "v"(s[n][3]));
            uint2 w; w.x = p0; w.y = p1;
            *reinterpret_cast<uint2*>(&Pl[wave][l15][n * 16 + lg * 4]) = w;
        }

        // ---- O^T += V^T P^T
        __builtin_amdgcn_s_setprio(1);
#pragma unroll
        for (int ks = 0; ks < 2; ++ks) {
            short8 pa = *reinterpret_cast<const short8*>(
                &Pl[wave][l15][ks * 32 + lg * 8]);
#pragma unroll
            for (int n = 0; n < 4; ++n) {
                int r = n * 16 + l15;
                int c8 = (ks * 4 + lg) ^ (r & 7);
                short8 vf = *reinterpret_cast<const short8*>(Vb + r * 128 + c8 * 16);
                o[n] = MFMA16(vf, pa, o[n]);
            }
        }
        __builtin_amdgcn_s_setprio(0);

        // ---- covered fence + raw barrier (no early drain)
        asm volatile("s_waitcnt vmcnt(0)" ::: "memory");
        __builtin_amdgcn_sched_barrier(0);
        __builtin_amdgcn_s_barrier();
    }

    // ---- combine deferred per-lane sums (once)
    float lsum = lpart + __shfl_xor(lpart, 16);
    lsum += __shfl_xor(lsum, 32);
    float inv = 1.f / lsum;

    __syncthreads();   // safe LDS reuse for epilogue
    float* Ol = (float*)&KVl[0][0][0] + wave * (16 * 68);
#pragma unroll
    for (int n = 0; n < 4; ++n) {
        float4 w;
        w.x = o[n][0] * inv; w.y = o[n][1] * inv;
        w.z = o[n][2] * inv; w.w = o[n][3] * inv;
        *reinterpret_cast<float4*>(&Ol[l15 * 68 + n * 16 + lg * 4]) = w;
    }
#pragma unroll
    for (int kk = 0; kk < 4; ++kk) {
        int r = lane >> 2, c0 = (lane & 3) * 4 + kk * 16;
        float4 v = *reinterpret_cast<const float4*>(&Ol[r * 68 + c0]);
        short4 b;
        b.x = f2bf(v.x); b.y = f2bf(v.y); b.z = f2bf(v.z); b.w = f2bf(v.w);
        *reinterpret_cast<short4*>(
            &Aout[(size_t)(q0w + r) * DM + h * DKH + c0]) = b;
    }
}

// ---------------------------------------------------------------- launcher
extern "C" void kernel_launch(void* const* d_in, const int* in_sizes, int n_in,
                              void* d_out, int out_size, void* d_ws, size_t ws_size,
                              hipStream_t stream) {
    const float* X  = (const float*)d_in[0];
    const int*   pos = (const int*)d_in[1];
    const float* Wq = (const float*)d_in[2];
    const float* Wk = (const float*)d_in[3];
    const float* Wv = (const float*)d_in[4];
    const float* Wo = (const float*)d_in[5];
    float* out = (float*)d_out;

    char* ws = (char*)d_ws;
    short* Xbf = (short*)ws;  ws += (size_t)S_LEN * DM * 2;
    short* Wqb = (short*)ws;  ws += (size_t)DM * DM * 2;
    short* Wkb = (short*)ws;  ws += (size_t)DM * DM * 2;
    short* Wvb = (short*)ws;  ws += (size_t)DM * DM * 2;
    short* Wob = (short*)ws;  ws += (size_t)DM * DM * 2;
    float2* rt = (float2*)ws; ws += (size_t)S_LEN * 32 * 8;
    short* Qb  = (short*)ws;  ws += (size_t)NH * S_LEN * DKH * 2;
    short* Kb  = (short*)ws;  ws += (size_t)NH * S_LEN * DKH * 2;
    short* Vtb = (short*)ws;  ws += (size_t)NH * S_LEN * DKH * 2;
    short* Ab  = (short*)ws;  ws += (size_t)S_LEN * DM * 2;

    prep_k<<<5888, 256, 0, stream>>>(X, Wq, Wk, Wv, Wo, pos,
                                     Xbf, Wqb, Wkb, Wvb, Wob, rt);
    gemm_qkv_k<<<dim3(6, 32, 3), 256, 0, stream>>>(Xbf, Wqb, Wkb, Wvb, rt, Qb, Kb, Vtb);
    attn_k<<<dim3(64 * NH), 256, 0, stream>>>(Qb, Kb, Vtb, Ab);
    gemm_out_k<<<dim3(6, 32), 256, 0, stream>>>(Ab, Wob, out);
}